// Round 1
// baseline (645.117 us; speedup 1.0000x reference)
//
#include <hip/hip_runtime.h>
#include <hip/hip_bf16.h>

// MoE router+dispatch+combine, fused single kernel.
//   logits = flat @ rw^T + rb          [T,64]   (bf16 hi/lo split x3 MFMA)
//   scores = softmax(logits); top8 -> w_k, idx_k, w_sum
//   out[t] = flat[t]*w_sum + sum_k w_k * eb[idx_k]
// T=16384, H=4096, E=64, K=8, fp32 in/out.

typedef float f32x4 __attribute__((ext_vector_type(4)));
typedef short s16x8 __attribute__((ext_vector_type(8)));   // 8 bf16 (4 VGPRs)

#define HH 4096
#define EE 64
#define KTOP 8
#define TT 32          // tokens per block
#define NT 256         // threads per block (4 waves, k-split 4x1024)

__device__ __forceinline__ short f2bf(float x) {
  __hip_bfloat16 h = __float2bfloat16(x);      // RNE
  return *reinterpret_cast<const short*>(&h);
}
__device__ __forceinline__ float bf2f(short s) {
  union { unsigned u; float f; } v;
  v.u = ((unsigned)(unsigned short)s) << 16;
  return v.f;
}

// Split 8 fp32 into bf16 hi + bf16 lo fragments (fp32 ~= hi + lo, err ~2^-18).
__device__ __forceinline__ void split8(const float4& a, const float4& b,
                                       s16x8& hi, s16x8& lo) {
  float x[8] = {a.x, a.y, a.z, a.w, b.x, b.y, b.z, b.w};
#pragma unroll
  for (int i = 0; i < 8; ++i) {
    short hb = f2bf(x[i]);
    float hf = bf2f(hb);
    short lb = f2bf(x[i] - hf);   // x - hi exact in fp32
    hi[i] = hb;
    lo[i] = lb;
  }
}

__global__ __launch_bounds__(NT, 2) void moe_router_combine(
    const float* __restrict__ flat,   // [T,H]
    const float* __restrict__ rw,     // [E,H]
    const float* __restrict__ rb,     // [E]
    const float* __restrict__ eb,     // [E,H]
    float* __restrict__ out) {        // [T,H]
  // lgP: per-wave partial logits (k-split), reduced in place into lgP[0].
  __shared__ float lgP[4][TT][EE + 2];       // +2 pad: bank spread
  __shared__ float twS[TT][KTOP + 1];        // 8 weights + w_sum
  __shared__ int   tiS[TT][KTOP];            // 8 expert indices

  const int tid  = threadIdx.x;
  const int lane = tid & 63;
  const int wv   = tid >> 6;                 // wave 0..3
  const int lrow = lane & 15;                // MFMA m/n index
  const int lkg  = lane >> 4;                // MFMA k-group
  const size_t t0 = (size_t)blockIdx.x * TT;

  // ---------------- Phase 1: logits via bf16x3 MFMA, k-split across waves ---
  f32x4 acc[2][4];                           // 2 m-tiles x 4 e-tiles
#pragma unroll
  for (int m = 0; m < 2; ++m)
#pragma unroll
    for (int e = 0; e < 4; ++e)
      acc[m][e] = (f32x4){0.f, 0.f, 0.f, 0.f};

  const int kbase = wv * (HH / 4) + lkg * 8; // this wave's k-range start
  const float* pA0 = flat + (t0 + lrow) * HH + kbase;        // tokens t0+0..15
  const float* pA1 = flat + (t0 + 16 + lrow) * HH + kbase;   // tokens t0+16..31
  const float* pW  = rw + (size_t)lrow * HH + kbase;         // experts (lrow) + et*16

  // raw fp32 buffers; software-pipelined: load(s+1) issued before MFMAs of s
  float4 a00, a01, a10, a11, w0[4], w1[4];
  {
    const int ko = 0;
    a00 = *(const float4*)(pA0 + ko);
    a01 = *(const float4*)(pA0 + ko + 4);
    a10 = *(const float4*)(pA1 + ko);
    a11 = *(const float4*)(pA1 + ko + 4);
#pragma unroll
    for (int et = 0; et < 4; ++et) {
      w0[et] = *(const float4*)(pW + (size_t)et * 16 * HH + ko);
      w1[et] = *(const float4*)(pW + (size_t)et * 16 * HH + ko + 4);
    }
  }

  for (int s = 0; s < 32; ++s) {             // 32 steps x K=32 = 1024 k per wave
    // convert current step's raw fp32 -> bf16 hi/lo fragments
    s16x8 Ah0, Al0, Ah1, Al1, Wh[4], Wl[4];
    split8(a00, a01, Ah0, Al0);
    split8(a10, a11, Ah1, Al1);
#pragma unroll
    for (int et = 0; et < 4; ++et) split8(w0[et], w1[et], Wh[et], Wl[et]);

    if (s + 1 < 32) {                        // prefetch next step (overlaps MFMAs)
      const int ko = (s + 1) * 32;
      a00 = *(const float4*)(pA0 + ko);
      a01 = *(const float4*)(pA0 + ko + 4);
      a10 = *(const float4*)(pA1 + ko);
      a11 = *(const float4*)(pA1 + ko + 4);
#pragma unroll
      for (int et = 0; et < 4; ++et) {
        w0[et] = *(const float4*)(pW + (size_t)et * 16 * HH + ko);
        w1[et] = *(const float4*)(pW + (size_t)et * 16 * HH + ko + 4);
      }
    }

    // 3-pass fp32 emulation: hh + hl + lh (lo*lo term ~2^-18, dropped)
#pragma unroll
    for (int et = 0; et < 4; ++et) {
      acc[0][et] = __builtin_amdgcn_mfma_f32_16x16x32_bf16(Ah0, Wh[et], acc[0][et], 0, 0, 0);
      acc[0][et] = __builtin_amdgcn_mfma_f32_16x16x32_bf16(Ah0, Wl[et], acc[0][et], 0, 0, 0);
      acc[0][et] = __builtin_amdgcn_mfma_f32_16x16x32_bf16(Al0, Wh[et], acc[0][et], 0, 0, 0);
      acc[1][et] = __builtin_amdgcn_mfma_f32_16x16x32_bf16(Ah1, Wh[et], acc[1][et], 0, 0, 0);
      acc[1][et] = __builtin_amdgcn_mfma_f32_16x16x32_bf16(Ah1, Wl[et], acc[1][et], 0, 0, 0);
      acc[1][et] = __builtin_amdgcn_mfma_f32_16x16x32_bf16(Al1, Wh[et], acc[1][et], 0, 0, 0);
    }
  }

  // C/D layout: col(expert) = lane&15, row(token) = (lane>>4)*4 + reg  [m89]
#pragma unroll
  for (int mt = 0; mt < 2; ++mt)
#pragma unroll
    for (int et = 0; et < 4; ++et)
#pragma unroll
      for (int r = 0; r < 4; ++r)
        lgP[wv][mt * 16 + (lane >> 4) * 4 + r][et * 16 + (lane & 15)] = acc[mt][et][r];
  __syncthreads();

  // reduce k-split partials + router bias, in place into lgP[0]
#pragma unroll
  for (int i = 0; i < (TT * EE) / NT; ++i) {   // 8 entries/thread
    int idx = tid + NT * i;
    int t = idx >> 6, e = idx & 63;
    float v = lgP[0][t][e] + lgP[1][t][e] + lgP[2][t][e] + lgP[3][t][e] + rb[e];
    lgP[0][t][e] = v;
  }
  __syncthreads();

  // ---------------- Phase 2: softmax + top-8, one wave per 8 tokens ---------
  for (int i = 0; i < TT / 4; ++i) {
    const int tl = wv * (TT / 4) + i;
    float l = lgP[0][tl][lane];              // lane = expert
    float m = l;
#pragma unroll
    for (int off = 32; off > 0; off >>= 1) m = fmaxf(m, __shfl_xor(m, off, 64));
    float p = __expf(l - m);
    float sum = p;
#pragma unroll
    for (int off = 32; off > 0; off >>= 1) sum += __shfl_xor(sum, off, 64);
    const float inv = 1.0f / sum;

    float cur = l;
    float wsum = 0.f;
    for (int k = 0; k < KTOP; ++k) {
      float v = cur;
      int a = lane;
#pragma unroll
      for (int off = 32; off > 0; off >>= 1) {
        float v2 = __shfl_xor(v, off, 64);
        int   a2 = __shfl_xor(a, off, 64);
        if (v2 > v || (v2 == v && a2 < a)) { v = v2; a = a2; }  // stable: low idx wins
      }
      float wk = __shfl(p, a, 64) * inv;
      wsum += wk;
      if (lane == 0) { twS[tl][k] = wk; tiS[tl][k] = a; }
      if (lane == a) cur = -1e30f;           // remove winner
    }
    if (lane == 0) twS[tl][KTOP] = wsum;
  }
  __syncthreads();

  // ---------------- Phase 3: combine (streaming, HBM-bound) -----------------
  const int HV = HH / 4;                     // float4s per row
  for (int i = 0; i < TT / 4; ++i) {
    const int tl = wv * (TT / 4) + i;
    const size_t tg = t0 + tl;
    const float wsm = twS[tl][KTOP];
    float wk[KTOP];
    const float4* ebp[KTOP];
#pragma unroll
    for (int k = 0; k < KTOP; ++k) {
      wk[k]  = twS[tl][k];
      ebp[k] = reinterpret_cast<const float4*>(eb + (size_t)tiS[tl][k] * HH);
    }
    const float4* fr   = reinterpret_cast<const float4*>(flat + tg * HH);
    float4*       orow = reinterpret_cast<float4*>(out + tg * HH);
#pragma unroll 2
    for (int h = lane; h < HV; h += 64) {
      float4 x = fr[h];
      float4 o;
      o.x = x.x * wsm; o.y = x.y * wsm; o.z = x.z * wsm; o.w = x.w * wsm;
#pragma unroll
      for (int k = 0; k < KTOP; ++k) {
        float4 b = ebp[k][h];
        o.x = fmaf(wk[k], b.x, o.x);
        o.y = fmaf(wk[k], b.y, o.y);
        o.z = fmaf(wk[k], b.z, o.z);
        o.w = fmaf(wk[k], b.w, o.w);
      }
      orow[h] = o;
    }
  }
}

extern "C" void kernel_launch(void* const* d_in, const int* in_sizes, int n_in,
                              void* d_out, int out_size, void* d_ws, size_t ws_size,
                              hipStream_t stream) {
  const float* flat = (const float*)d_in[0];   // hidden_states [4,4096,4096]
  const float* rw   = (const float*)d_in[1];   // router_weight [64,4096]
  const float* rb   = (const float*)d_in[2];   // router_bias [64]
  const float* eb   = (const float*)d_in[3];   // expert_bias [64,4096]
  float* out = (float*)d_out;

  const int T = in_sizes[0] / HH;              // 16384
  const int nblk = T / TT;                     // 512
  moe_router_combine<<<dim3(nblk), dim3(NT), 0, stream>>>(flat, rw, rb, eb, out);
}